// Round 1
// baseline (414.363 us; speedup 1.0000x reference)
//
#include <hip/hip_runtime.h>
#include <math.h>

#define BB 16
#define CC 64
#define HH 224
#define WW 224
#define HWSZ (HH * WW)          // 50176
#define HW4 (HWSZ / 4)          // 12544
#define CHW4 (CC * HW4)         // 802816

// -------- Kernel 1: channel-wise mean + max -> feat planes [B][2][H][W] -----
__global__ __launch_bounds__(256) void reduce_kernel(const float* __restrict__ x,
                                                     float* __restrict__ feat) {
    int idx = blockIdx.x * 256 + threadIdx.x;     // over B*HW/4 = 200704, exact
    int b   = idx / HW4;
    int hw4 = idx - b * HW4;

    const float4* xp = reinterpret_cast<const float4*>(x) + (size_t)b * CHW4 + hw4;
    float4 v = xp[0];
    float4 s = v;
    float4 m = v;
#pragma unroll 8
    for (int c = 1; c < CC; ++c) {
        float4 t = xp[(size_t)c * HW4];
        s.x += t.x; s.y += t.y; s.z += t.z; s.w += t.w;
        m.x = fmaxf(m.x, t.x); m.y = fmaxf(m.y, t.y);
        m.z = fmaxf(m.z, t.z); m.w = fmaxf(m.w, t.w);
    }
    const float inv = 1.0f / 64.0f;
    s.x *= inv; s.y *= inv; s.z *= inv; s.w *= inv;

    float4* avgp = reinterpret_cast<float4*>(feat) + (size_t)b * 2 * HW4 + hw4;
    float4* maxp = avgp + HW4;
    *avgp = s;
    *maxp = m;
}

// -------- Kernel 2: 7x7 conv (2->1 ch, pad 3) + bias + sigmoid -> gate ------
__global__ __launch_bounds__(256) void conv_kernel(const float* __restrict__ feat,
                                                   const float* __restrict__ cw,
                                                   const float* __restrict__ cb,
                                                   float* __restrict__ gate) {
    int idx = blockIdx.x * 256 + threadIdx.x;     // over B*HW = 802816, exact
    int b  = idx / HWSZ;
    int hw = idx - b * HWSZ;
    int h  = hw / WW;
    int w  = hw - h * WW;

    const float* fa = feat + (size_t)b * 2 * HWSZ;   // avg plane
    const float* fm = fa + HWSZ;                     // max plane

    float acc = cb[0];
#pragma unroll
    for (int kh = 0; kh < 7; ++kh) {
        int hh = h + kh - 3;
        if ((unsigned)hh >= (unsigned)HH) continue;
#pragma unroll
        for (int kw = 0; kw < 7; ++kw) {
            int ww = w + kw - 3;
            if ((unsigned)ww >= (unsigned)WW) continue;
            int o = hh * WW + ww;
            acc = fmaf(fa[o], cw[kh * 7 + kw], acc);
            acc = fmaf(fm[o], cw[49 + kh * 7 + kw], acc);
        }
    }
    gate[idx] = 1.0f / (1.0f + expf(-acc));
}

// -------- Kernel 3: out = x * gate (broadcast over channels), float4 --------
__global__ __launch_bounds__(256) void mul_kernel(const float* __restrict__ x,
                                                  const float* __restrict__ gate,
                                                  float* __restrict__ out) {
    int idx = blockIdx.x * 256 + threadIdx.x;     // over B*C*HW/4 = 12845056, exact
    int b   = idx / CHW4;
    int r   = idx - b * CHW4;
    int hw4 = r % HW4;

    float4 v = reinterpret_cast<const float4*>(x)[idx];
    float4 g = reinterpret_cast<const float4*>(gate)[(size_t)b * HW4 + hw4];
    v.x *= g.x; v.y *= g.y; v.z *= g.z; v.w *= g.w;
    reinterpret_cast<float4*>(out)[idx] = v;
}

extern "C" void kernel_launch(void* const* d_in, const int* in_sizes, int n_in,
                              void* d_out, int out_size, void* d_ws, size_t ws_size,
                              hipStream_t stream) {
    const float* x  = (const float*)d_in[0];   // [16,64,224,224]
    const float* cw = (const float*)d_in[1];   // [1,2,7,7]
    const float* cb = (const float*)d_in[2];   // [1]
    float* out = (float*)d_out;

    float* feat = (float*)d_ws;                       // B*2*HW floats = 6.4 MB
    float* gate = feat + (size_t)BB * 2 * HWSZ;       // B*HW floats   = 3.2 MB

    reduce_kernel<<<(BB * HW4) / 256, 256, 0, stream>>>(x, feat);
    conv_kernel<<<(BB * HWSZ) / 256, 256, 0, stream>>>(feat, cw, cb, gate);
    mul_kernel<<<(BB * CHW4) / 256, 256, 0, stream>>>(x, gate, out);
}

// Round 2
// 407.165 us; speedup vs baseline: 1.0177x; 1.0177x over previous
//
#include <hip/hip_runtime.h>
#include <math.h>

#define BB 16
#define CC 64
#define HH 224
#define WW 224
#define HWSZ (HH * WW)          // 50176
#define HW4 (HWSZ / 4)          // 12544
#define R 14                    // gate rows per tile (224/14 = 16 tiles)
#define TILES (HH / R)          // 16
#define FR (R + 6)              // 20 feat rows incl ±3 halo
#define FW 240                  // padded LDS feat row width: 3 left pad + 224 + right pad
#define W4 (WW / 4)             // 56
#define T 512                   // threads per block (8 waves)

__global__ __launch_bounds__(T) void fused_kernel(const float* __restrict__ x,
                                                  const float* __restrict__ cw,
                                                  const float* __restrict__ cb,
                                                  float* __restrict__ out) {
    __shared__ float fa[FR * FW];               // avg plane (zero-padded borders)
    __shared__ float fm[FR * FW];               // max plane
    __shared__ alignas(16) float gate[R * WW];  // sigmoid(conv) result
    __shared__ float wt[98];                    // conv weights [2][7][7]

    const int blk = blockIdx.x;                 // 0..255
    const int b   = blk >> 4;                   // TILES == 16
    const int tb  = blk & 15;
    const int h0  = tb * R;                     // first gate row of this tile
    const int t   = threadIdx.x;

    // ---- zero-fill feat planes (gives conv its zero padding) + stage weights
    for (int i = t; i < FR * FW; i += T) { fa[i] = 0.f; fm[i] = 0.f; }
    if (t < 98) wt[t] = cw[t];
    __syncthreads();

    // ---- phase 1: channel mean+max over 64 ch -> feat LDS (rows h0-3 .. h0+R+2)
    const float4* xb = reinterpret_cast<const float4*>(x) + (size_t)b * (CC * HW4);
    for (int p = t; p < FR * W4; p += T) {      // 1120 float4 pixels
        int pr = p / W4;
        int pc = p - pr * W4;
        int gh = h0 - 3 + pr;                   // global row
        if ((unsigned)gh >= (unsigned)HH) continue;   // stays zero (padding)
        const float4* xp = xb + gh * W4 + pc;
        float4 s = make_float4(0.f, 0.f, 0.f, 0.f);
        float4 m = make_float4(-INFINITY, -INFINITY, -INFINITY, -INFINITY);
#pragma unroll 8
        for (int c = 0; c < CC; ++c) {
            float4 u = xp[(size_t)c * HW4];
            s.x += u.x; s.y += u.y; s.z += u.z; s.w += u.w;
            m.x = fmaxf(m.x, u.x); m.y = fmaxf(m.y, u.y);
            m.z = fmaxf(m.z, u.z); m.w = fmaxf(m.w, u.w);
        }
        const float inv = 1.0f / 64.0f;
        int o = pr * FW + 3 + pc * 4;           // +3 = left zero pad
        fa[o + 0] = s.x * inv; fa[o + 1] = s.y * inv;
        fa[o + 2] = s.z * inv; fa[o + 3] = s.w * inv;
        fm[o + 0] = m.x; fm[o + 1] = m.y; fm[o + 2] = m.z; fm[o + 3] = m.w;
    }
    __syncthreads();

    // ---- phase 2: 7x7 conv (2->1) + bias + sigmoid -> gate LDS
    const float bias = cb[0];
    for (int p = t; p < R * WW; p += T) {       // 3136 gate pixels
        int r = p / WW;
        int w = p - r * WW;
        float acc = bias;
#pragma unroll
        for (int kh = 0; kh < 7; ++kh) {
            int ro = (r + kh) * FW + w;         // LDS col w+kw == global col w+kw-3 (+3 pad)
#pragma unroll
            for (int kw = 0; kw < 7; ++kw) {
                acc = fmaf(fa[ro + kw], wt[kh * 7 + kw], acc);
                acc = fmaf(fm[ro + kw], wt[49 + kh * 7 + kw], acc);
            }
        }
        gate[p] = 1.0f / (1.0f + expf(-acc));
    }
    __syncthreads();

    // ---- phase 3: out = x * gate for all 64 channels of this tile
    float4* ob = reinterpret_cast<float4*>(out) + (size_t)b * (CC * HW4);
    const float4* g4 = reinterpret_cast<const float4*>(gate);
    const int NP = R * W4;                      // 784 float4 per channel plane
    for (int i = t; i < CC * NP; i += T) {      // 50176 = 98 * 512, perfectly balanced
        int c  = i / NP;
        int p  = i - c * NP;
        int pr = p / W4;
        int pc = p - pr * W4;
        size_t off = (size_t)c * HW4 + (size_t)(h0 + pr) * W4 + pc;
        float4 v = xb[off];
        float4 g = g4[p];
        v.x *= g.x; v.y *= g.y; v.z *= g.z; v.w *= g.w;
        ob[off] = v;
    }
}

extern "C" void kernel_launch(void* const* d_in, const int* in_sizes, int n_in,
                              void* d_out, int out_size, void* d_ws, size_t ws_size,
                              hipStream_t stream) {
    const float* x  = (const float*)d_in[0];   // [16,64,224,224]
    const float* cw = (const float*)d_in[1];   // [1,2,7,7]
    const float* cb = (const float*)d_in[2];   // [1]
    float* out = (float*)d_out;

    fused_kernel<<<BB * TILES, T, 0, stream>>>(x, cw, cb, out);
}